// Round 3
// baseline (153.495 us; speedup 1.0000x reference)
//
#include <hip/hip_runtime.h>
#include <math.h>

#define NPARAMS 104                         // N_LAYERS * N_QUBITS
#define DIM 8192
#define NELEM ((size_t)DIM * (size_t)DIM)   // 67108864 floats, 268.4 MB
#define RB 2048                             // blocks
#define RT 256                              // threads/block
#define F4B (NELEM / 4 / RB)                // 8192 float4 per block (contiguous 128 KB)
#define ITERS (int)(F4B / RT)               // 32 loads/thread, no remainder

typedef __attribute__((ext_vector_type(4))) float f32x4;

// ---------------------------------------------------------------------------
// Single fused kernel. Each block reduces a contiguous 128 KB chunk of H with
// 8 nontemporal dwordx4 loads in flight (VGPR <= 64 via launch_bounds -> 8
// waves/SIMD), writes a double partial, takes a ticket; the last block sums
// the partials, computes the analytic global phase e^{i*sum(theta)/2}, and
// writes energy + uniform state. Counter is re-zeroed every replay by a
// captured hipMemsetAsync node -> deterministic, replay-safe.
// ---------------------------------------------------------------------------
__global__ __launch_bounds__(RT, 8) void vqe_fused(
    const float* __restrict__ H,
    const float* __restrict__ params,
    float* __restrict__ out,
    unsigned int* __restrict__ counter,
    double* __restrict__ partials)
{
    const f32x4* __restrict__ H4 = reinterpret_cast<const f32x4*>(H);
    const size_t base = (size_t)blockIdx.x * F4B + threadIdx.x;

    // --- streaming partial sum: 4 independent fp32 accumulators ---
    float a0 = 0.f, a1 = 0.f, a2 = 0.f, a3 = 0.f;
    #pragma unroll 1
    for (int i = 0; i < ITERS; i += 8) {
        f32x4 v0 = __builtin_nontemporal_load(H4 + base + (size_t)(i + 0) * RT);
        f32x4 v1 = __builtin_nontemporal_load(H4 + base + (size_t)(i + 1) * RT);
        f32x4 v2 = __builtin_nontemporal_load(H4 + base + (size_t)(i + 2) * RT);
        f32x4 v3 = __builtin_nontemporal_load(H4 + base + (size_t)(i + 3) * RT);
        f32x4 v4 = __builtin_nontemporal_load(H4 + base + (size_t)(i + 4) * RT);
        f32x4 v5 = __builtin_nontemporal_load(H4 + base + (size_t)(i + 5) * RT);
        f32x4 v6 = __builtin_nontemporal_load(H4 + base + (size_t)(i + 6) * RT);
        f32x4 v7 = __builtin_nontemporal_load(H4 + base + (size_t)(i + 7) * RT);
        a0 += (v0[0] + v0[1]) + (v0[2] + v0[3]);
        a1 += (v1[0] + v1[1]) + (v1[2] + v1[3]);
        a2 += (v2[0] + v2[1]) + (v2[2] + v2[3]);
        a3 += (v3[0] + v3[1]) + (v3[2] + v3[3]);
        a0 += (v4[0] + v4[1]) + (v4[2] + v4[3]);
        a1 += (v5[0] + v5[1]) + (v5[2] + v5[3]);
        a2 += (v6[0] + v6[1]) + (v6[2] + v6[3]);
        a3 += (v7[0] + v7[1]) + (v7[2] + v7[3]);
    }
    double acc = (double)((a0 + a1) + (a2 + a3));

    // --- wave-64 + LDS block reduce ---
    #pragma unroll
    for (int off = 32; off > 0; off >>= 1)
        acc += __shfl_down(acc, off, 64);

    __shared__ double wsum[RT / 64];
    __shared__ int last_sh;
    const int lane = threadIdx.x & 63;
    const int wid  = threadIdx.x >> 6;
    if (lane == 0) wsum[wid] = acc;
    __syncthreads();

    if (threadIdx.x == 0) {
        double t = (wsum[0] + wsum[1]) + (wsum[2] + wsum[3]);
        partials[blockIdx.x] = t;
        __threadfence();                          // release partial device-wide
        unsigned int tk = atomicAdd(counter, 1u); // device-scope ticket
        last_sh = (tk == RB - 1) ? 1 : 0;
    }
    __syncthreads();
    if (last_sh == 0) return;

    // --- last block: final sum + analytic phase + outputs ---
    __threadfence();                              // acquire all partials
    volatile const double* vp = partials;
    double s = 0.0;
    #pragma unroll
    for (int i = threadIdx.x; i < RB; i += RT) s += vp[i];

    #pragma unroll
    for (int off = 32; off > 0; off >>= 1)
        s += __shfl_down(s, off, 64);
    if (lane == 0) wsum[wid] = s;
    __syncthreads();
    const double total = (wsum[0] + wsum[1]) + (wsum[2] + wsum[3]);

    // renormalized product of unit phasors == phasor of the summed angles
    float ang = 0.f;
    for (int k = 0; k < NPARAMS; ++k) ang += params[k];
    ang *= 0.5f;
    const float pr = cosf(ang);
    const float pq = sinf(ang);
    const float invsq = 1.0f / sqrtf((float)DIM);
    const float sr = pr * invsq;
    const float si = pq * invsq;

    for (int j = threadIdx.x; j < DIM; j += RT) {
        out[1 + 2 * j] = sr;
        out[2 + 2 * j] = si;
    }
    if (threadIdx.x == 0) {
        const double norm2 = (double)sr * sr + (double)si * si;  // ~1/8192
        out[0] = (float)(total * norm2);
    }
}

extern "C" void kernel_launch(void* const* d_in, const int* in_sizes, int n_in,
                              void* d_out, int out_size, void* d_ws, size_t ws_size,
                              hipStream_t stream) {
    const float* params = (const float*)d_in[0];   // 104 floats
    const float* H      = (const float*)d_in[1];   // 8192*8192 floats
    float* out          = (float*)d_out;           // [energy, re0, im0, ...]
    unsigned int* counter = (unsigned int*)d_ws;              // 4 B ticket
    double* partials      = (double*)((char*)d_ws + 256);     // RB doubles

    hipMemsetAsync(counter, 0, sizeof(unsigned int), stream); // captured node
    vqe_fused<<<RB, RT, 0, stream>>>(H, params, out, counter, partials);
    (void)in_sizes; (void)n_in; (void)out_size; (void)ws_size;
}

// Round 4
// 59.331 us; speedup vs baseline: 2.5871x; 2.5871x over previous
//
#include <hip/hip_runtime.h>
#include <math.h>

#define NPARAMS 104                         // N_LAYERS * N_QUBITS
#define DIM 8192
#define NELEM ((size_t)DIM * (size_t)DIM)   // 67108864 floats, 268.4 MB
#define RB 2048                             // reduce blocks
#define RT 256                              // threads/block
#define NTHREADS ((size_t)RB * RT)          // 524288
#define N4 (NELEM / 4)                      // 16777216 float4
#define ITERS (int)(N4 / NTHREADS)          // exactly 32

typedef __attribute__((ext_vector_type(4))) float f32x4;

// ---------------------------------------------------------------------------
// Kernel 1: globally-strided float4 partial reduce (R2's proven sweep
// pattern). 8 dwordx4 loads in flight per thread (unroll-1 outer loop),
// 4 independent fp32 accumulators -> ~56 VGPR -> full 32 waves/CU.
// One float partial per block. No atomics/fences -> replay-safe.
// ---------------------------------------------------------------------------
__global__ __launch_bounds__(RT) void vqe_reduce(
    const float* __restrict__ H, float* __restrict__ partials) {
    const f32x4* __restrict__ H4 = reinterpret_cast<const f32x4*>(H);
    const size_t tid = (size_t)blockIdx.x * RT + threadIdx.x;

    float a0 = 0.f, a1 = 0.f, a2 = 0.f, a3 = 0.f;
    #pragma unroll 1
    for (int i = 0; i < ITERS; i += 8) {
        f32x4 v0 = H4[tid + (size_t)(i + 0) * NTHREADS];
        f32x4 v1 = H4[tid + (size_t)(i + 1) * NTHREADS];
        f32x4 v2 = H4[tid + (size_t)(i + 2) * NTHREADS];
        f32x4 v3 = H4[tid + (size_t)(i + 3) * NTHREADS];
        f32x4 v4 = H4[tid + (size_t)(i + 4) * NTHREADS];
        f32x4 v5 = H4[tid + (size_t)(i + 5) * NTHREADS];
        f32x4 v6 = H4[tid + (size_t)(i + 6) * NTHREADS];
        f32x4 v7 = H4[tid + (size_t)(i + 7) * NTHREADS];
        a0 += (v0[0] + v0[1]) + (v0[2] + v0[3]);
        a1 += (v1[0] + v1[1]) + (v1[2] + v1[3]);
        a2 += (v2[0] + v2[1]) + (v2[2] + v2[3]);
        a3 += (v3[0] + v3[1]) + (v3[2] + v3[3]);
        a0 += (v4[0] + v4[1]) + (v4[2] + v4[3]);
        a1 += (v5[0] + v5[1]) + (v5[2] + v5[3]);
        a2 += (v6[0] + v6[1]) + (v6[2] + v6[3]);
        a3 += (v7[0] + v7[1]) + (v7[2] + v7[3]);
    }
    float acc = (a0 + a1) + (a2 + a3);

    // wave-64 shuffle reduction
    #pragma unroll
    for (int off = 32; off > 0; off >>= 1)
        acc += __shfl_down(acc, off, 64);

    __shared__ float wsum[RT / 64];
    const int lane = threadIdx.x & 63;
    const int wid  = threadIdx.x >> 6;
    if (lane == 0) wsum[wid] = acc;
    __syncthreads();

    if (threadIdx.x == 0)
        partials[blockIdx.x] = (wsum[0] + wsum[1]) + (wsum[2] + wsum[3]);
}

// ---------------------------------------------------------------------------
// Kernel 2: fp64 sum of 2048 float partials; analytic global phase
// e^{i*sum(theta)/2}; write energy + uniform state (interleaved re/im).
// ---------------------------------------------------------------------------
__global__ __launch_bounds__(RT) void vqe_finalize(
    const float* __restrict__ partials,
    const float* __restrict__ params, float* __restrict__ out) {

    double s = 0.0;
    #pragma unroll
    for (int i = threadIdx.x; i < RB; i += RT) s += (double)partials[i];

    #pragma unroll
    for (int off = 32; off > 0; off >>= 1)
        s += __shfl_down(s, off, 64);

    __shared__ double wsum[RT / 64];
    __shared__ double total_sh;
    const int lane = threadIdx.x & 63;
    const int wid  = threadIdx.x >> 6;
    if (lane == 0) wsum[wid] = s;
    __syncthreads();
    if (threadIdx.x == 0)
        total_sh = (wsum[0] + wsum[1]) + (wsum[2] + wsum[3]);
    __syncthreads();

    // renormalized product of unit phasors == phasor of the summed angles
    float ang = 0.f;
    for (int k = 0; k < NPARAMS; ++k) ang += params[k];
    ang *= 0.5f;
    const float pr = cosf(ang);
    const float pq = sinf(ang);
    const float invsq = 1.0f / sqrtf((float)DIM);
    const float sr = pr * invsq;
    const float si = pq * invsq;

    for (int j = threadIdx.x; j < DIM; j += RT) {
        out[1 + 2 * j] = sr;
        out[2 + 2 * j] = si;
    }
    if (threadIdx.x == 0) {
        const double norm2 = (double)sr * sr + (double)si * si;  // ~1/8192
        out[0] = (float)(total_sh * norm2);
    }
}

extern "C" void kernel_launch(void* const* d_in, const int* in_sizes, int n_in,
                              void* d_out, int out_size, void* d_ws, size_t ws_size,
                              hipStream_t stream) {
    const float* params = (const float*)d_in[0];   // 104 floats
    const float* H      = (const float*)d_in[1];   // 8192*8192 floats
    float* out          = (float*)d_out;           // [energy, re0, im0, ...]
    float* partials     = (float*)d_ws;            // RB floats of scratch

    vqe_reduce<<<RB, RT, 0, stream>>>(H, partials);
    vqe_finalize<<<1, RT, 0, stream>>>(partials, params, out);
    (void)in_sizes; (void)n_in; (void)out_size; (void)ws_size;
}